// Round 5
// baseline (238.044 us; speedup 1.0000x reference)
//
#include <hip/hip_runtime.h>

// PCEN: x (32,128,8000) f32, log_s (128,) f32 -> out (32,128,8000) f32
//   s = exp(log_s[f]); a = 1-s
//   M[t] = a*M[t-1] + s*x[t], M[0] = x[0]
//   out  = sqrt(x * (1e-6 + M)^-0.98 + 2) - sqrt(2)
//
// R5 structure: ONE WAVE PER SEQUENCE. 4096 waves = 1024 blocks x 4 waves;
// 31 x 256-element iterations + 64-element tail per wave. No halo (exact
// serial scan per row), contiguous 32 KB read + 32 KB write streams per
// wave, XCD-swizzled so each XCD owns a contiguous 16 MB slab.
//
// History:
//  R1 ds_bpermute->DPP row ops: null => not LDS-crossbar-bound.
//  R2 balanced chunks + unroll: null (compiler re-serialized, VGPR 20).
//  R3 hand-hoisted 10-deep load burst (VGPR 44, pipeline real): null.
//     (Also introduced a bug: log_s loaded AFTER the burst => iter0 waited
//     for all 10 KB. Fixed here: s-load fires first.)
//  R4 NT store -> plain store: null. WRITE_SIZE exactly 128 MB => no
//     background drain; fillBufferAligned does 6.6 TB/s at 9.5% occupancy
//     on the same chip => write path is fine; reads gate the pipeline at
//     ~3 B/cy/CU despite 126 KB/CU outstanding.
//  R5 theory: the surviving invariant is the work SHAPE -- 16K short bursty
//     waves, 10 KB each, round-robin XCD interleave, 10% halo, per-wave
//     serial log_s load + trans-heavy preamble per 10 KB. Restructure to
//     copy-like long streams: 4x fewer waves, 4x amortization, zero halo,
//     contiguous per-XCD slabs, s-load overlapped.

#define T_LEN 8000
#define F_DIM 128
#define NSEQ  4096          // B*F
#define MAIN_IT 31          // 31*256 = 7936 elements; +64-element tail

typedef __attribute__((ext_vector_type(4))) float vfloat4;

// NOTE: __builtin_amdgcn_logf IS log2 (see __clang_hip_math.h __log2f)
__device__ __forceinline__ float hw_log2(float v) { return __builtin_amdgcn_logf(v); }
__device__ __forceinline__ float hw_exp2(float v) { return __builtin_amdgcn_exp2f(v); }

__device__ __forceinline__ float pcen_out(float xi, float m) {
    float p = hw_exp2(-0.98f * hw_log2(1e-6f + m));
    return __builtin_amdgcn_sqrtf(fmaf(xi, p, 2.0f)) - 1.4142135623730951f;
}

// DPP mov with 0-fill: rows disabled by RMASK and lanes with invalid sources
// (bound_ctrl) produce 0.0f, so fmaf(w, dpp0<..>(P), P) is a no-op there.
template<int CTRL, int RMASK>
__device__ __forceinline__ float dpp0(float v) {
    return __int_as_float(__builtin_amdgcn_update_dpp(
        0, __float_as_int(v), CTRL, RMASK, 0xF, true));
}

// Weighted (linear-recurrence) inclusive scan over 64 lanes, VALU pipe only.
// dk1..dk8 = d, d^2, d^4, d^8 (d = per-lane-step decay);
// w15 = d^((l&15)+1), w31 = d^((l&31)+1) row-crossing weights.
__device__ __forceinline__ float wscan64(float P, float dk1, float dk2, float dk4,
                                         float dk8, float w15, float w31) {
    P = fmaf(dk1, dpp0<0x111, 0xF>(P), P);   // row_shr:1
    P = fmaf(dk2, dpp0<0x112, 0xF>(P), P);   // row_shr:2
    P = fmaf(dk4, dpp0<0x114, 0xF>(P), P);   // row_shr:4
    P = fmaf(dk8, dpp0<0x118, 0xF>(P), P);   // row_shr:8
    P = fmaf(w15, dpp0<0x142, 0xA>(P), P);   // row_bcast:15 -> rows 1,3
    P = fmaf(w31, dpp0<0x143, 0xC>(P), P);   // row_bcast:31 -> rows 2,3
    return P;
}

__global__ __launch_bounds__(256, 4) void pcen_kernel(const float* __restrict__ x,
                                                      const float* __restrict__ log_s,
                                                      float* __restrict__ out) {
    const int lane = threadIdx.x & 63;
    const int widx = threadIdx.x >> 6;
    const int bid  = blockIdx.x;
    // XCD swizzle: blocks round-robin across 8 XCDs, so give XCD k the
    // contiguous block range [k*128, (k+1)*128) => sequences [k*512,(k+1)*512)
    // = one contiguous 16 MB read slab + 16 MB write slab per XCD.
    const int swz  = (bid & 7) * 128 + (bid >> 3);   // bijective on [0,1024)
    const int seq  = swz * 4 + widx;                 // b*128 + f
    const int f    = seq & (F_DIM - 1);

    const float* xp = x   + (size_t)seq * T_LEN;
    float*       op = out + (size_t)seq * T_LEN;

    const float ls = log_s[f];           // fire FIRST; s-chain hides under loads

    const float4* xv4 = (const float4*)xp;
    vfloat4*      ov4 = (vfloat4*)op;

    // 4-deep prefetch ring + tail prefetch
    float4 p0 = xv4[0 * 64 + lane];
    float4 p1 = xv4[1 * 64 + lane];
    float4 p2 = xv4[2 * 64 + lane];
    float4 p3 = xv4[3 * 64 + lane];
    float  xt = xp[7936 + lane];         // tail elements, one per lane

    // Per-wave constants (trans chain overlaps the first loads' latency)
    const float s   = hw_exp2(ls * 1.4426950408889634f);
    const float a   = 1.0f - s;
    const float l2a = hw_log2(a);

    const float a2 = a * a;
    const float a3 = a2 * a;
    const float a4 = a2 * a2;
    const float c0 = a4;        // a^4
    const float c1 = c0 * c0;   // a^8
    const float c2 = c1 * c1;   // a^16
    const float c3 = c2 * c2;   // a^32
    const float c4 = c3 * c3;   // a^64
    const float c5 = c4 * c4;   // a^128
    const float a256 = c5 * c5; // a^256
    const float a4l = hw_exp2((float)(4 * lane) * l2a); // a^(4*lane)
    const float inv_a4 = 1.0f / a4;                     // exclusive recovery
    const float w15 = hw_exp2((float)(4 * ((lane & 15) + 1)) * l2a);
    const float w31 = hw_exp2((float)(4 * ((lane & 31) + 1)) * l2a);

    // Exact scan: carry = x[0] (lane 0's first loaded element). With lane0
    // C = carry, m0 = a*x0 + s*x0 = x0 = M[0] exactly.
    float carry = __int_as_float(__builtin_amdgcn_readlane(__float_as_int(p0.x), 0));

    #pragma unroll 1
    for (int it = 0; it < MAIN_IT; ++it) {
        float4 xv = p0;
        p0 = p1; p1 = p2; p2 = p3;
        if (it + 4 < MAIN_IT) p3 = xv4[(it + 4) * 64 + lane];   // wave-uniform

        // local 4-element scan (zero entering state)
        float B0 = s * xv.x;
        float B1 = fmaf(a, B0, s * xv.y);
        float B2 = fmaf(a, B1, s * xv.z);
        float B3 = fmaf(a, B2, s * xv.w);

        // wave-wide weighted scan (decay a^4 per lane)
        float P = wscan64(B3, c0, c1, c2, c3, w15, w31);

        // exclusive entering state: P = B3 + a^4*E  =>  E = (P - B3)/a^4
        float E = (P - B3) * inv_a4;
        float C = fmaf(a4l, carry, E);      // state entering this lane's 4-chunk

        float P63 = __int_as_float(__builtin_amdgcn_readlane(__float_as_int(P), 63));
        carry = fmaf(a256, carry, P63);

        float m0 = fmaf(a,  C, B0);
        float m1 = fmaf(a2, C, B1);
        float m2 = fmaf(a3, C, B2);
        float m3 = fmaf(a4, C, B3);
        vfloat4 o;
        o.x = pcen_out(xv.x, m0);
        o.y = pcen_out(xv.y, m1);
        o.z = pcen_out(xv.z, m2);
        o.w = pcen_out(xv.w, m3);
        ov4[it * 64 + lane] = o;            // plain store (R4: NT==plain)
    }

    // tail: 64 elements, t = 7936..7999, one per lane (decay = a)
    {
        const float al1  = hw_exp2((float)(lane + 1) * l2a);        // a^(lane+1)
        const float w15t = hw_exp2((float)((lane & 15) + 1) * l2a); // a^((l&15)+1)
        const float w31t = hw_exp2((float)((lane & 31) + 1) * l2a); // a^((l&31)+1)
        float P = wscan64(s * xt, a, a2, a4, c1, w15t, w31t);
        float m = fmaf(al1, carry, P);
        op[7936 + lane] = pcen_out(xt, m);
    }
}

extern "C" void kernel_launch(void* const* d_in, const int* in_sizes, int n_in,
                              void* d_out, int out_size, void* d_ws, size_t ws_size,
                              hipStream_t stream) {
    const float* x     = (const float*)d_in[0];
    const float* log_s = (const float*)d_in[1];
    float*       out   = (float*)d_out;
    // 4096 sequences, 1 wave each: 1024 blocks x 256 threads (4 blocks/CU)
    pcen_kernel<<<dim3(1024), dim3(256), 0, stream>>>(x, log_s, out);
}

// Round 6
// 217.993 us; speedup vs baseline: 1.0920x; 1.0920x over previous
//
#include <hip/hip_runtime.h>

// PCEN: x (32,128,8000) f32, log_s (128,) f32 -> out (32,128,8000) f32
//   s = exp(log_s[f]); a = 1-s
//   M[t] = a*M[t-1] + s*x[t], M[0] = x[0]
//   out  = sqrt(x * (1e-6 + M)^-0.98 + 2) - sqrt(2)
//
// One wave per CHUNK of a sequence; 4 chunks/seq => 16384 waves (R4's best
// shape, 79.0us). Chunks >0 rebuild IIR state from a 512-element halo
// (R6: was 768): a^512 ~ 2.4e-6 for a=0.975 -- error ~1e-6 in M, far under
// the ~0.096 harness threshold (current absmax 0.0039). Saves 16 MB reads.
//
// History of nulls (all ~80-84us): R1 shuffle->DPP (not crossbar), R2
// balanced+unroll (compiler re-serialized), R3 10-deep hoisted load burst
// (VGPR 44, pipeline real -- not load-MLP), R4 NT->plain stores (write path
// fine; fillBufferAligned does 6.6 TB/s write-only on this chip), R5 one-
// wave-per-seq + XCD slabs (shape/locality innocent; FETCH 64 MB => x is
// half-L3-resident across harness iterations).
// R6 theory: the un-varied invariant is CACHE POLICY. Our 1.6 TB/s write
// stream write-allocates through L2/L3 and churns the same hierarchy that
// serves half our reads (L3-resident x) => read service queues behind
// allocation/eviction, implied per-request latency ~10K cyc while HBM sits
// at 31% and every pipe idles. Mixed-stream kernels WITHOUT this pattern
// (RMSNorm m146) do 4.89 TB/s on this chip. Fix under test: non-temporal
// on BOTH streams (NT loads never tried before) -- take the kernel out of
// the caches entirely.

#define T_LEN 8000
#define F_DIM 128
#define NSEQ  4096          // B*F
#define HALO_ITERS 2        // 512-element warm-up

typedef __attribute__((ext_vector_type(4))) float vfloat4;

// NOTE: __builtin_amdgcn_logf IS log2 (see __clang_hip_math.h __log2f)
__device__ __forceinline__ float hw_log2(float v) { return __builtin_amdgcn_logf(v); }
__device__ __forceinline__ float hw_exp2(float v) { return __builtin_amdgcn_exp2f(v); }

__device__ __forceinline__ float pcen_out(float xi, float m) {
    float p = hw_exp2(-0.98f * hw_log2(1e-6f + m));
    return __builtin_amdgcn_sqrtf(fmaf(xi, p, 2.0f)) - 1.4142135623730951f;
}

// DPP mov with 0-fill: rows disabled by RMASK and lanes with invalid sources
// (bound_ctrl) produce 0.0f, so fmaf(w, dpp0<..>(P), P) is a no-op there.
template<int CTRL, int RMASK>
__device__ __forceinline__ float dpp0(float v) {
    return __int_as_float(__builtin_amdgcn_update_dpp(
        0, __float_as_int(v), CTRL, RMASK, 0xF, true));
}

// Weighted (linear-recurrence) inclusive scan over 64 lanes, VALU pipe only.
__device__ __forceinline__ float wscan64(float P, float dk1, float dk2, float dk4,
                                         float dk8, float w15, float w31) {
    P = fmaf(dk1, dpp0<0x111, 0xF>(P), P);   // row_shr:1
    P = fmaf(dk2, dpp0<0x112, 0xF>(P), P);   // row_shr:2
    P = fmaf(dk4, dpp0<0x114, 0xF>(P), P);   // row_shr:4
    P = fmaf(dk8, dpp0<0x118, 0xF>(P), P);   // row_shr:8
    P = fmaf(w15, dpp0<0x142, 0xA>(P), P);   // row_bcast:15 -> rows 1,3
    P = fmaf(w31, dpp0<0x143, 0xC>(P), P);   // row_bcast:31 -> rows 2,3
    return P;
}

__global__ __launch_bounds__(256, 4) void pcen_kernel(const float* __restrict__ x,
                                                      const float* __restrict__ log_s,
                                                      float* __restrict__ out) {
    const int lane  = threadIdx.x & 63;
    const int wid   = blockIdx.x * 4 + (threadIdx.x >> 6);
    const int seq   = wid >> 2;          // b*128 + f
    const int chunk = wid & 3;
    const int f     = seq & (F_DIM - 1);

    const float* xp = x   + (size_t)seq * T_LEN;
    float*       op = out + (size_t)seq * T_LEN;

    const float ls = log_s[f];           // fire FIRST (R3/R4 had this after the burst)

    // chunk0: 10 output iters (t 0..2559). chunks1-3: 2 halo + 7 output
    // iters (1792 each): c1 t2560.., c2 t4352.., c3 t6144..7935 + 64 tail.
    const int halo = (chunk == 0) ? 0 : HALO_ITERS;
    const int S    = (chunk == 0) ? 0 : 2560 + (chunk - 1) * 1792;
    const int base = S - halo * 256;     // c1:2048 c2:3840 c3:5632 (all >=0)

    const vfloat4* xv4 = (const vfloat4*)(xp + base);
    vfloat4*       ov4 = (vfloat4*)(op + base);

    // ---- hoisted NT load burst: all loads older than all stores ----------
    vfloat4 r0 = __builtin_nontemporal_load(&xv4[0 * 64 + lane]);
    vfloat4 r1 = __builtin_nontemporal_load(&xv4[1 * 64 + lane]);
    vfloat4 r2 = __builtin_nontemporal_load(&xv4[2 * 64 + lane]);
    vfloat4 r3 = __builtin_nontemporal_load(&xv4[3 * 64 + lane]);
    vfloat4 r4 = __builtin_nontemporal_load(&xv4[4 * 64 + lane]);
    vfloat4 r5 = __builtin_nontemporal_load(&xv4[5 * 64 + lane]);
    vfloat4 r6 = __builtin_nontemporal_load(&xv4[6 * 64 + lane]);
    vfloat4 r7 = __builtin_nontemporal_load(&xv4[7 * 64 + lane]);
    vfloat4 r8 = __builtin_nontemporal_load(&xv4[8 * 64 + lane]);
    vfloat4 r9 = {0.0f, 0.0f, 0.0f, 0.0f};
    if (chunk == 0) r9 = __builtin_nontemporal_load(&xv4[9 * 64 + lane]); // 10th iter
    float xt = 0.0f;
    if (chunk == 3) xt = __builtin_nontemporal_load(xp + 7936 + lane);    // tail
    __builtin_amdgcn_sched_barrier(0);   // pin: nothing sinks below the burst
    // ----------------------------------------------------------------------

    const float s   = hw_exp2(ls * 1.4426950408889634f);
    const float a   = 1.0f - s;
    const float l2a = hw_log2(a);

    const float a2 = a * a;
    const float a3 = a2 * a;
    const float a4 = a2 * a2;
    const float c0 = a4;        // a^4
    const float c1 = c0 * c0;   // a^8
    const float c2 = c1 * c1;   // a^16
    const float c3 = c2 * c2;   // a^32
    const float c4 = c3 * c3;   // a^64
    const float c5 = c4 * c4;   // a^128
    const float a256 = c5 * c5; // a^256
    const float a4l = hw_exp2((float)(4 * lane) * l2a); // a^(4*lane)
    const float inv_a4 = 1.0f / a4;                     // exclusive recovery
    const float w15 = hw_exp2((float)(4 * ((lane & 15) + 1)) * l2a);
    const float w31 = hw_exp2((float)(4 * ((lane & 31) + 1)) * l2a);

    // chunk0 seed: x[0] is lane 0 of r0 (base==0 there). Lane0 then gets
    // C = carry => m0 = a*x0 + s*x0 = x0 = M[0] exactly.
    float carry = (chunk == 0)
        ? __int_as_float(__builtin_amdgcn_readlane(__float_as_int(r0.x), 0))
        : 0.0f;

#define PCEN_IT(xv, kk)                                                        \
    {                                                                          \
        float B0 = s * xv.x;                                                   \
        float B1 = fmaf(a, B0, s * xv.y);                                      \
        float B2 = fmaf(a, B1, s * xv.z);                                      \
        float B3 = fmaf(a, B2, s * xv.w);                                      \
        float P  = wscan64(B3, c0, c1, c2, c3, w15, w31);                      \
        float E  = (P - B3) * inv_a4;                                          \
        float C  = fmaf(a4l, carry, E);                                        \
        float P63 = __int_as_float(                                            \
            __builtin_amdgcn_readlane(__float_as_int(P), 63));                 \
        carry = fmaf(a256, carry, P63);                                        \
        if ((kk) >= halo) {   /* wave-uniform */                               \
            float m0 = fmaf(a,  C, B0);                                        \
            float m1 = fmaf(a2, C, B1);                                        \
            float m2 = fmaf(a3, C, B2);                                        \
            float m3 = fmaf(a4, C, B3);                                        \
            vfloat4 o;                                                         \
            o.x = pcen_out(xv.x, m0);                                          \
            o.y = pcen_out(xv.y, m1);                                          \
            o.z = pcen_out(xv.z, m2);                                          \
            o.w = pcen_out(xv.w, m3);                                          \
            __builtin_nontemporal_store(o, &ov4[(kk) * 64 + lane]);            \
        }                                                                      \
    }

    PCEN_IT(r0, 0)
    PCEN_IT(r1, 1)
    PCEN_IT(r2, 2)
    PCEN_IT(r3, 3)
    PCEN_IT(r4, 4)
    PCEN_IT(r5, 5)
    PCEN_IT(r6, 6)
    PCEN_IT(r7, 7)
    PCEN_IT(r8, 8)
    if (chunk == 0) PCEN_IT(r9, 9)       // wave-uniform 10th iteration
#undef PCEN_IT

    // chunk 3 tail: 64 elements, t = 7936..7999, one per lane (decay = a)
    if (chunk == 3) {
        const float al1  = hw_exp2((float)(lane + 1) * l2a);        // a^(lane+1)
        const float w15t = hw_exp2((float)((lane & 15) + 1) * l2a); // a^((l&15)+1)
        const float w31t = hw_exp2((float)((lane & 31) + 1) * l2a); // a^((l&31)+1)
        float P = wscan64(s * xt, a, a2, a4, c1, w15t, w31t);
        float m = fmaf(al1, carry, P);
        op[7936 + lane] = pcen_out(xt, m);
    }
}

extern "C" void kernel_launch(void* const* d_in, const int* in_sizes, int n_in,
                              void* d_out, int out_size, void* d_ws, size_t ws_size,
                              hipStream_t stream) {
    const float* x     = (const float*)d_in[0];
    const float* log_s = (const float*)d_in[1];
    float*       out   = (float*)d_out;
    // 4096 seqs x 4 chunks = 16384 waves; 4 waves per 256-thread block
    pcen_kernel<<<dim3(NSEQ), dim3(256), 0, stream>>>(x, log_s, out);
}